// Round 10
// baseline (162.045 us; speedup 1.0000x reference)
//
#include <hip/hip_runtime.h>
#include <stdint.h>

// VectorQuantizer on MI355X — round 16: halve phase-B LDS volume (quarter
// pairing) + DMA phase A. R15 post-mortem: C-gather fix bought only 2.5us;
// remaining 46us has no saturated pipe. Largest reducible floor: phase-B
// a-frag ds_read_b128 (2048/CU x 12cyc ~ 10us) — a_[mi] is QUARTER-
// INVARIANT but was re-read every quarter (4x over-read of Xbf).
// R16: (1) process 2 quarters concurrently: acc[2][2][4]=64 regs, a-reads
// 128->64/wave (LDS 1MB->512KB/block). ch-loop fully unrolled, barrier-free
// -> compiler pipelines b-loads across iterations (m97 evidence), no
// explicit prefetch regs (live ~110-125 <= 128 cap at (512,4)).
// (2) Phase A via global_load_lds into double-buffered Xf[2][16KB]:
// DMA(s+1) under convert(s), 1 barrier/slab (was 2), no VGPR round-trip
// (R13's pattern, unconfounded — its regression was the x[8] spill).
// (3) scoring once per pair (2 sweeps vs 4).
// Numerics bit-identical: same ch=0..7 chain per acc, same fadd(e2,-2*acc),
// ascending-code strict-< first-min -> absmax must stay 0.001930237.
// Tripwires: symmetric FETCH/WRITE excess = spill; absmax change = bug.
// latent [32,256,1024] fp32, codebook [1024,256] fp32.
// ws = [ Ebf bf16 chunk-planar [dq32][code1024][8] (512 KB) | e2 f32[1024] ].

#define D_   256
#define HW_  1024
#define N_   32768
#define K_   1024

typedef __attribute__((ext_vector_type(8))) short  s8v;   // 8 bf16 (4 VGPR)
typedef __attribute__((ext_vector_type(4))) float  f4v;   // MFMA acc

__device__ __forceinline__ ushort bf16rne(float x) {
  unsigned u = __float_as_uint(x);
  return (ushort)((u + 0x7FFFu + ((u >> 16) & 1u)) >> 16);
}

// monotone map: unsigned order of key == float order (handles negatives)
__device__ __forceinline__ unsigned fkey(float f) {
  unsigned u = __float_as_uint(f);
  return u ^ (unsigned)(((int)u >> 31) | 0x80000000);
}

// async global->LDS DMA, 16 B/lane; LDS dest = wave-uniform base + lane*16
__device__ __forceinline__ void gld_lds16(const void* g, void* l) {
  __builtin_amdgcn_global_load_lds(
      (const __attribute__((address_space(1))) unsigned int*)g,
      (__attribute__((address_space(3))) unsigned int*)l, 16, 0, 0);
}

// ---------- codebook -> bf16 chunk-planar Ebf + numpy-pairwise e2 + loss=0 ----------
// (R15 verbatim)
__global__ __launch_bounds__(256) void k_eprep(const float* __restrict__ cb,
                                               ushort* __restrict__ Ebf,
                                               float* __restrict__ e2,
                                               float* __restrict__ loss) {
  const int t = threadIdx.x, blk = blockIdx.x;   // 128 blocks x 8 codes
  if (blk == 0 && t == 0) *loss = 0.f;
  {
    int dq = t & 31, cl = t >> 5;                // dq fast -> coalesced reads
    const float* src = cb + (size_t)(blk * 8 + cl) * 256 + dq * 8;
    float4 v0 = ((const float4*)src)[0], v1 = ((const float4*)src)[1];
    ushort tmp[8] __attribute__((aligned(16)));
    tmp[0] = bf16rne(v0.x); tmp[1] = bf16rne(v0.y);
    tmp[2] = bf16rne(v0.z); tmp[3] = bf16rne(v0.w);
    tmp[4] = bf16rne(v1.x); tmp[5] = bf16rne(v1.y);
    tmp[6] = bf16rne(v1.z); tmp[7] = bf16rne(v1.w);
    *(uint4*)(Ebf + ((size_t)dq * 1024 + blk * 8 + cl) * 8) = *(uint4*)tmp;
  }
  // e2 numpy-pairwise: 16 lanes/row, butterfly reproduces pairwise tree
  if (t < 128) {
    const int row = blk * 8 + (t >> 4);
    const int sub = t & 15, j = sub & 7, h = sub >> 3;
    const float* base = cb + row * 256 + h * 128 + j;
    float r = __fmul_rn(base[0], base[0]);
    for (int i = 1; i < 16; ++i) {
      float v = base[8 * i];
      r = __fadd_rn(r, __fmul_rn(v, v));
    }
#pragma unroll
    for (int m = 1; m < 16; m <<= 1) r = __fadd_rn(r, __shfl_xor(r, m, 64));
    if (sub == 0) e2[row] = r;
  }
}

// ---------- fused: convert + MFMA-argmin over K=1024 + gather + out + loss ----------
// Grid 512 tiles (64 pos, hw-contiguous). Block 512 = 8 waves.
// LDS: Xbf 32 KB [dq32][pos64][8]; Xf dbuf 2x16 KB [d64][pos64] f32;
// e2s 4 KB; bests 512 B -> ~69 KB -> 2 blocks/CU -> 16 waves/CU.
// Phase B: 2 pairs x 8 ch; wave w covers codes {(2p+qq)*256 + w*32 ..+31};
// acc[2][2][4] swapped (rows=codes); b-frags direct from L2-resident Ebf;
// barrier-free; per-lane running argmin, single final reduce.
__global__ __launch_bounds__(512, 4) void k_fused(
    const float* __restrict__ latent, const float* __restrict__ cb,
    const ushort* __restrict__ Ebf, const float* __restrict__ e2g,
    float* __restrict__ out, float* __restrict__ loss) {
  __shared__ alignas(16) ushort Xbf[32 * 64 * 8];    // 32 KB
  __shared__ alignas(16) float Xf[2][64 * 64];       // 2x16 KB (phase A dbuf)
  __shared__ alignas(16) float e2s[1024];            // 4 KB
  __shared__ unsigned long long bests[64];           // 512 B
  __shared__ float red[8];

  const int t = threadIdx.x, tile = blockIdx.x;      // 512 tiles x 64 pos
  const int b = tile >> 4, hw0 = (tile & 15) * 64;
  const int lane = t & 63, w = t >> 6;               // wave 0..7
  const int lrow = lane & 15, q = lane >> 4;

  ((float2*)e2s)[t] = ((const float2*)e2g)[t];       // 1024 floats, 512 thr
  if (t < 64) bests[t] = ~0ull;

  const float* Lb = latent + (size_t)b * (D_ * HW_) + hw0;

  // DMA latent slab S (64 d x 64 pos f32 = 16 KB) -> Xf[S&1] as [d][pos]
#define DMA_XF(S)                                                         \
  {                                                                       \
    float* XfD = Xf[(S) & 1];                                             \
    _Pragma("unroll")                                                     \
    for (int ii = 0; ii < 2; ++ii) {                                      \
      int jj = w * 2 + ii;                          /* 4 d-rows each */   \
      gld_lds16(Lb + (size_t)((S) * 64 + jj * 4 + (lane >> 4)) * HW_      \
                    + (lane & 15) * 4,                                    \
                XfD + jj * 256 + lane * 4);                               \
    }                                                                     \
  }

  // ---- Phase A: 4 pipelined slabs, 1 barrier each; convert in-register ----
  DMA_XF(0);
#pragma unroll 1
  for (int s = 0; s < 4; ++s) {
    asm volatile("s_waitcnt vmcnt(0)" ::: "memory"); // my DMA(s) landed
    __builtin_amdgcn_sched_barrier(0);
    __builtin_amdgcn_s_barrier();                    // all waves: slab s in LDS
    __builtin_amdgcn_sched_barrier(0);
    if (s < 3) DMA_XF(s + 1);                        // fill other buffer
    const float* Xs = Xf[s & 1];
    const int pos = t & 63, dqs = t >> 6;            // dqs 0..7 in slab
    ushort tmp[8] __attribute__((aligned(16)));
#pragma unroll
    for (int e = 0; e < 8; ++e) tmp[e] = bf16rne(Xs[(dqs * 8 + e) * 64 + pos]);
    *(uint4*)&Xbf[((size_t)(s * 8 + dqs) * 64 + pos) * 8] = *(uint4*)tmp;
  }
  __syncthreads();                                   // Xbf/e2s/bests ready

  // ---- Phase B: 2 pairs x 8 ch, barrier-free; a-frags read ONCE per ch ----
  float bv[4];                                       // per-lane running argmin
  int bk[4];
#pragma unroll
  for (int mi = 0; mi < 4; ++mi) { bv[mi] = 3.4e38f; bk[mi] = 0; }

#pragma unroll 1
  for (int p = 0; p < 2; ++p) {                      // pair = quarters {2p,2p+1}
    f4v acc[2][2][4];                                // [qq][kj][mi]
#pragma unroll
    for (int qq = 0; qq < 2; ++qq)
#pragma unroll
      for (int kj = 0; kj < 2; ++kj)
#pragma unroll
        for (int mi = 0; mi < 4; ++mi) acc[qq][kj][mi] = (f4v){0.f, 0.f, 0.f, 0.f};

#pragma unroll
    for (int ch = 0; ch < 8; ++ch) {                 // chunks of 32 d (unrolled:
      s8v a_[4];                                     // compiler pipelines loads)
#pragma unroll
      for (int mi = 0; mi < 4; ++mi)
        a_[mi] = *(const s8v*)&Xbf[((size_t)(ch * 4 + q) * 64 + mi * 16 + lrow) * 8];
      s8v b_[2][2];
#pragma unroll
      for (int qq = 0; qq < 2; ++qq)
#pragma unroll
        for (int kj = 0; kj < 2; ++kj)               // L2-hit, 256 B contig/q-grp
          b_[qq][kj] = *(const s8v*)(Ebf +
              ((size_t)(ch * 4 + q) * 1024 + (2 * p + qq) * 256 + w * 32 +
               kj * 16 + lrow) * 8);
#pragma unroll
      for (int qq = 0; qq < 2; ++qq)
#pragma unroll
        for (int kj = 0; kj < 2; ++kj)
#pragma unroll
          for (int mi = 0; mi < 4; ++mi)             // SWAPPED: rows=codes
            acc[qq][kj][mi] = __builtin_amdgcn_mfma_f32_16x16x32_bf16(
                b_[qq][kj], a_[mi], acc[qq][kj][mi], 0, 0, 0);
    }
    // score both quarters of this pair (ascending code order, strict <)
#pragma unroll
    for (int mi = 0; mi < 4; ++mi)
#pragma unroll
      for (int qq = 0; qq < 2; ++qq)
#pragma unroll
        for (int kj = 0; kj < 2; ++kj)
#pragma unroll
          for (int reg = 0; reg < 4; ++reg) {
            int code = (2 * p + qq) * 256 + w * 32 + kj * 16 + q * 4 + reg;
            float s = __fadd_rn(e2s[code], -2.f * acc[qq][kj][mi][reg]);
            if (s < bv[mi]) { bv[mi] = s; bk[mi] = code; }
          }
  }
  // single final cross-lane reduce + cross-wave merge (min is associative)
#pragma unroll
  for (int mi = 0; mi < 4; ++mi) {
    float v = bv[mi];
    int k2 = bk[mi];
#pragma unroll
    for (int m = 16; m < 64; m <<= 1) {              // reduce over q: 2 steps
      float ov = __shfl_xor(v, m, 64);
      int ok = __shfl_xor(k2, m, 64);
      if (ov < v || (ov == v && ok < k2)) { v = ov; k2 = ok; }
    }
    if (q == 0)
      atomicMin(&bests[mi * 16 + lrow],
                ((unsigned long long)fkey(v) << 32) | (unsigned)k2);
  }
  __syncthreads();                                   // bests final

  // ---- Phase C: float4 gathers + straight-through output + loss (R15) ----
  const int posq = t & 15;                           // pos-group of 4
  const int dsub = t >> 4;                           // 0..31
  int kk[4];
#pragma unroll
  for (int e = 0; e < 4; ++e)
    kk[e] = (int)(unsigned)(bests[posq * 4 + e] & 0xFFFFFFFFull);
  float* Ob = out + (size_t)b * (D_ * HW_) + hw0 + posq * 4;
  const float* Lb2 = Lb + posq * 4;
  float part = 0.f;
#pragma unroll
  for (int mit = 0; mit < 2; ++mit) {
    const int dq4 = mit * 32 + dsub;                 // d-quad 0..63
    float4 qv4[4];
#pragma unroll
    for (int e = 0; e < 4; ++e)                      // 64 B contig per row/4 lanes
      qv4[e] = *(const float4*)(cb + (size_t)kk[e] * 256 + dq4 * 4);
#pragma unroll
    for (int j = 0; j < 4; ++j) {
      const int d = dq4 * 4 + j;
      float4 x = *(const float4*)(Lb2 + (size_t)d * HW_);
      float4 o;
      float qv, df;
      qv = ((const float*)&qv4[0])[j]; df = __fsub_rn(qv, x.x); o.x = __fadd_rn(x.x, df); part = fmaf(df, df, part);
      qv = ((const float*)&qv4[1])[j]; df = __fsub_rn(qv, x.y); o.y = __fadd_rn(x.y, df); part = fmaf(df, df, part);
      qv = ((const float*)&qv4[2])[j]; df = __fsub_rn(qv, x.z); o.z = __fadd_rn(x.z, df); part = fmaf(df, df, part);
      qv = ((const float*)&qv4[3])[j]; df = __fsub_rn(qv, x.w); o.w = __fadd_rn(x.w, df); part = fmaf(df, df, part);
      *(float4*)(Ob + (size_t)d * HW_) = o;          // x + (q - x), NOT q
    }
  }
#pragma unroll
  for (int off = 32; off > 0; off >>= 1) part += __shfl_down(part, off, 64);
  if (lane == 0) red[w] = part;
  __syncthreads();
  if (t == 0) {
    float tot = 0.f;
#pragma unroll
    for (int i = 0; i < 8; ++i) tot += red[i];
    atomicAdd(loss, tot * (1.25f / 8388608.0f));
  }
}

extern "C" void kernel_launch(void* const* d_in, const int* in_sizes, int n_in,
                              void* d_out, int out_size, void* d_ws, size_t ws_size,
                              hipStream_t stream) {
  const float* latent = (const float*)d_in[0];
  const float* cb     = (const float*)d_in[1];
  float* out  = (float*)d_out;
  float* loss = out + (size_t)N_ * D_;             // element 8,388,608
  ushort* Ebf = (ushort*)d_ws;                     // 512 KB chunk-planar bf16
  float*  e2  = (float*)((char*)d_ws + (size_t)K_ * D_ * sizeof(ushort));

  hipLaunchKernelGGL(k_eprep, dim3(128), dim3(256), 0, stream, cb, Ebf, e2, loss);
  hipLaunchKernelGGL(k_fused, dim3(512), dim3(512), 0, stream,
                     latent, cb, Ebf, e2, out, loss);
}

// Round 11
// 107.753 us; speedup vs baseline: 1.5039x; 1.5039x over previous
//
#include <hip/hip_runtime.h>
#include <stdint.h>

// VectorQuantizer on MI355X — round 17: R15 + C_w=64 (halve a-frag re-reads),
// register-disciplined. R16 post-mortem: symmetric FETCH/WRITE excess
// (165/164 MB) = spill; fully-unrolled ch-loop + acc64+a16+b16 blew the
// 128-reg cap. Both R16 changes reverted; the surviving idea (cut a-read
// duplication) re-applied with honest accounting:
//   wave tile 64 pos x 64 codes, 2 halves of 512 codes. acc[4][4]=64 regs
//   + a_16 + b_16 + bv/bk 8 + addr ~10 = ~114 < 128. No prefetch array,
//   g-loop ROLLED (unroll 1, 16 iters) so liveness can't accumulate.
//   a-reads/block: 1024 -> 512 (saves ~5us/CU LDS-pipe time).
//   TLP hides b-load latency: 4 waves/SIMD x ~78cyc MFMA/iter ~ 250cyc L2.
// Scores bit-identical (same ch=0..7 chain); argmin = min over (score,code)
// pairs, partition-independent; per-lane codes ascend (half,kj,reg) with
// strict < -> absmax must stay 0.001930237 (tripwire).
// Spill tripwire: symmetric FETCH/WRITE excess over ~37/32.8 MB.
// Phase A, phase C, k_eprep: R15 verbatim.
// latent [32,256,1024] fp32, codebook [1024,256] fp32.
// ws = [ Ebf bf16 chunk-planar [dq32][code1024][8] (512 KB) | e2 f32[1024] ].

#define D_   256
#define HW_  1024
#define N_   32768
#define K_   1024

typedef __attribute__((ext_vector_type(8))) short  s8v;   // 8 bf16 (4 VGPR)
typedef __attribute__((ext_vector_type(4))) float  f4v;   // MFMA acc

__device__ __forceinline__ ushort bf16rne(float x) {
  unsigned u = __float_as_uint(x);
  return (ushort)((u + 0x7FFFu + ((u >> 16) & 1u)) >> 16);
}

// monotone map: unsigned order of key == float order (handles negatives)
__device__ __forceinline__ unsigned fkey(float f) {
  unsigned u = __float_as_uint(f);
  return u ^ (unsigned)(((int)u >> 31) | 0x80000000);
}

// ---------- codebook -> bf16 chunk-planar Ebf + numpy-pairwise e2 + loss=0 ----------
// (R15 verbatim)
__global__ __launch_bounds__(256) void k_eprep(const float* __restrict__ cb,
                                               ushort* __restrict__ Ebf,
                                               float* __restrict__ e2,
                                               float* __restrict__ loss) {
  const int t = threadIdx.x, blk = blockIdx.x;   // 128 blocks x 8 codes
  if (blk == 0 && t == 0) *loss = 0.f;
  {
    int dq = t & 31, cl = t >> 5;                // dq fast -> coalesced reads
    const float* src = cb + (size_t)(blk * 8 + cl) * 256 + dq * 8;
    float4 v0 = ((const float4*)src)[0], v1 = ((const float4*)src)[1];
    ushort tmp[8] __attribute__((aligned(16)));
    tmp[0] = bf16rne(v0.x); tmp[1] = bf16rne(v0.y);
    tmp[2] = bf16rne(v0.z); tmp[3] = bf16rne(v0.w);
    tmp[4] = bf16rne(v1.x); tmp[5] = bf16rne(v1.y);
    tmp[6] = bf16rne(v1.z); tmp[7] = bf16rne(v1.w);
    *(uint4*)(Ebf + ((size_t)dq * 1024 + blk * 8 + cl) * 8) = *(uint4*)tmp;
  }
  // e2 numpy-pairwise: 16 lanes/row, butterfly reproduces pairwise tree
  if (t < 128) {
    const int row = blk * 8 + (t >> 4);
    const int sub = t & 15, j = sub & 7, h = sub >> 3;
    const float* base = cb + row * 256 + h * 128 + j;
    float r = __fmul_rn(base[0], base[0]);
    for (int i = 1; i < 16; ++i) {
      float v = base[8 * i];
      r = __fadd_rn(r, __fmul_rn(v, v));
    }
#pragma unroll
    for (int m = 1; m < 16; m <<= 1) r = __fadd_rn(r, __shfl_xor(r, m, 64));
    if (sub == 0) e2[row] = r;
  }
}

// ---------- fused: convert + MFMA-argmin over K=1024 + gather + out + loss ----------
// Grid 512 tiles (64 pos, hw-contiguous). Block 512 = 8 waves.
// LDS ~55 KB (Xbf 32 + Xf 17.4 + e2s 4) -> 2 blocks/CU -> 16 waves/CU.
// Phase B: barrier-free; 2 halves x 8 ch rolled loop; wave w covers codes
// {half*512 + w*64 .. +63}; acc[4][4] swapped (rows=codes); b-frags direct
// from L2-resident Ebf; per-lane running argmin, single final reduce.
__global__ __launch_bounds__(512, 4) void k_fused(
    const float* __restrict__ latent, const float* __restrict__ cb,
    const ushort* __restrict__ Ebf, const float* __restrict__ e2g,
    float* __restrict__ out, float* __restrict__ loss) {
  __shared__ alignas(16) ushort Xbf[32 * 64 * 8];    // 32 KB
  __shared__ alignas(16) float Xf[64 * 68];          // 17.4 KB (phase A)
  __shared__ alignas(16) float e2s[1024];            // 4 KB
  __shared__ unsigned long long bests[64];           // 512 B
  __shared__ float red[8];

  const int t = threadIdx.x, tile = blockIdx.x;      // 512 tiles x 64 pos
  const int b = tile >> 4, hw0 = (tile & 15) * 64;
  const int lane = t & 63, w = t >> 6;               // wave 0..7
  const int lrow = lane & 15, q = lane >> 4;

  ((float2*)e2s)[t] = ((const float2*)e2g)[t];       // 1024 floats, 512 thr
  if (t < 64) bests[t] = ~0ull;

  // ---- Phase A: latent tile -> Xbf (bf16, chunk-planar), via Xf ----
  const float* Lb = latent + (size_t)b * (D_ * HW_) + hw0;
  for (int s = 0; s < 4; ++s) {                      // slabs of 64 d
    __syncthreads();
#pragma unroll
    for (int it = 0; it < 2; ++it) {                 // [64 d][64 hw] float4
      int id = it * 512 + t;
      int d = id >> 4, hq = id & 15;
      *(float4*)&Xf[d * 68 + hq * 4] =
          *(const float4*)(Lb + (size_t)(s * 64 + d) * HW_ + hq * 4);
    }
    __syncthreads();
    {                                                // transpose-convert
      int pos = t & 63, dqs = t >> 6;                // dqs 0..7 in slab
      ushort tmp[8] __attribute__((aligned(16)));
#pragma unroll
      for (int e = 0; e < 8; ++e) tmp[e] = bf16rne(Xf[(dqs * 8 + e) * 68 + pos]);
      *(uint4*)&Xbf[((size_t)(s * 8 + dqs) * 64 + pos) * 8] = *(uint4*)tmp;
    }
  }
  __syncthreads();                                   // Xbf/e2s/bests ready

  // ---- Phase B: rolled 16-phase loop (half = g>>3, ch = g&7), barrier-free ----
  f4v acc[4][4];                                     // [code-sub kj][pos-sub mi]
  float bv[4];                                       // per-lane running argmin
  int bk[4];
#pragma unroll
  for (int mi = 0; mi < 4; ++mi) { bv[mi] = 3.4e38f; bk[mi] = 0; }

#pragma unroll 1
  for (int g = 0; g < 16; ++g) {
    const int ch = g & 7, kh = (g >> 3) << 9;        // half base 0 / 512
    if (ch == 0) {
#pragma unroll
      for (int kj = 0; kj < 4; ++kj)
#pragma unroll
        for (int mi = 0; mi < 4; ++mi) acc[kj][mi] = (f4v){0.f, 0.f, 0.f, 0.f};
    }
    s8v b_[4];
#pragma unroll
    for (int kj = 0; kj < 4; ++kj)                   // L2-hit, 256 B contig/q-grp
      b_[kj] = *(const s8v*)(Ebf +
          ((size_t)(ch * 4 + q) * 1024 + kh + w * 64 + kj * 16 + lrow) * 8);
    s8v a_[4];
#pragma unroll
    for (int mi = 0; mi < 4; ++mi)
      a_[mi] = *(const s8v*)&Xbf[((size_t)(ch * 4 + q) * 64 + mi * 16 + lrow) * 8];
#pragma unroll
    for (int kj = 0; kj < 4; ++kj)
#pragma unroll
      for (int mi = 0; mi < 4; ++mi)                 // SWAPPED: rows=codes
        acc[kj][mi] = __builtin_amdgcn_mfma_f32_16x16x32_bf16(
            b_[kj], a_[mi], acc[kj][mi], 0, 0, 0);

    if (ch == 7) {                                   // per-half scoring
#pragma unroll
      for (int mi = 0; mi < 4; ++mi)
#pragma unroll
        for (int kj = 0; kj < 4; ++kj)               // ascending code order:
#pragma unroll
          for (int reg = 0; reg < 4; ++reg) {        // strict < = first-min
            int code = kh + w * 64 + kj * 16 + q * 4 + reg;
            float s = __fadd_rn(e2s[code], -2.f * acc[kj][mi][reg]);
            if (s < bv[mi]) { bv[mi] = s; bk[mi] = code; }
          }
    }
  }
  // single final cross-lane reduce + cross-wave merge (min is associative)
#pragma unroll
  for (int mi = 0; mi < 4; ++mi) {
    float v = bv[mi];
    int k2 = bk[mi];
#pragma unroll
    for (int m = 16; m < 64; m <<= 1) {              // reduce over q: 2 steps
      float ov = __shfl_xor(v, m, 64);
      int ok = __shfl_xor(k2, m, 64);
      if (ov < v || (ov == v && ok < k2)) { v = ov; k2 = ok; }
    }
    if (q == 0)
      atomicMin(&bests[mi * 16 + lrow],
                ((unsigned long long)fkey(v) << 32) | (unsigned)k2);
  }
  __syncthreads();                                   // bests final

  // ---- Phase C: float4 gathers + straight-through output + loss (R15) ----
  const int posq = t & 15;                           // pos-group of 4
  const int dsub = t >> 4;                           // 0..31
  int kk[4];
#pragma unroll
  for (int e = 0; e < 4; ++e)
    kk[e] = (int)(unsigned)(bests[posq * 4 + e] & 0xFFFFFFFFull);
  float* Ob = out + (size_t)b * (D_ * HW_) + hw0 + posq * 4;
  const float* Lb2 = Lb + posq * 4;
  float part = 0.f;
#pragma unroll
  for (int mit = 0; mit < 2; ++mit) {
    const int dq4 = mit * 32 + dsub;                 // d-quad 0..63
    float4 qv4[4];
#pragma unroll
    for (int e = 0; e < 4; ++e)                      // 64 B contig per row/4 lanes
      qv4[e] = *(const float4*)(cb + (size_t)kk[e] * 256 + dq4 * 4);
#pragma unroll
    for (int j = 0; j < 4; ++j) {
      const int d = dq4 * 4 + j;
      float4 x = *(const float4*)(Lb2 + (size_t)d * HW_);
      float4 o;
      float qv, df;
      qv = ((const float*)&qv4[0])[j]; df = __fsub_rn(qv, x.x); o.x = __fadd_rn(x.x, df); part = fmaf(df, df, part);
      qv = ((const float*)&qv4[1])[j]; df = __fsub_rn(qv, x.y); o.y = __fadd_rn(x.y, df); part = fmaf(df, df, part);
      qv = ((const float*)&qv4[2])[j]; df = __fsub_rn(qv, x.z); o.z = __fadd_rn(x.z, df); part = fmaf(df, df, part);
      qv = ((const float*)&qv4[3])[j]; df = __fsub_rn(qv, x.w); o.w = __fadd_rn(x.w, df); part = fmaf(df, df, part);
      *(float4*)(Ob + (size_t)d * HW_) = o;          // x + (q - x), NOT q
    }
  }
#pragma unroll
  for (int off = 32; off > 0; off >>= 1) part += __shfl_down(part, off, 64);
  if (lane == 0) red[w] = part;
  __syncthreads();
  if (t == 0) {
    float tot = 0.f;
#pragma unroll
    for (int i = 0; i < 8; ++i) tot += red[i];
    atomicAdd(loss, tot * (1.25f / 8388608.0f));
  }
}

extern "C" void kernel_launch(void* const* d_in, const int* in_sizes, int n_in,
                              void* d_out, int out_size, void* d_ws, size_t ws_size,
                              hipStream_t stream) {
  const float* latent = (const float*)d_in[0];
  const float* cb     = (const float*)d_in[1];
  float* out  = (float*)d_out;
  float* loss = out + (size_t)N_ * D_;             // element 8,388,608
  ushort* Ebf = (ushort*)d_ws;                     // 512 KB chunk-planar bf16
  float*  e2  = (float*)((char*)d_ws + (size_t)K_ * D_ * sizeof(ushort));

  hipLaunchKernelGGL(k_eprep, dim3(128), dim3(256), 0, stream, cb, Ebf, e2, loss);
  hipLaunchKernelGGL(k_fused, dim3(512), dim3(512), 0, stream,
                     latent, cb, Ebf, e2, out, loss);
}